// Round 8
// baseline (252.980 us; speedup 1.0000x reference)
//
#include <hip/hip_runtime.h>
#include <math.h>

#define N_PTS   16384
#define F_DIM   64
#define K_BINS  32
#define C_DIM   128
#define FK      2048      // F*K
#define NB32    (N_PTS / 32)   // 512 n-blocks of 32
#define CW      132       // W row stride: [w0..w127, S1, B, pad0, pad0]
#define EPS_F   1e-8f

typedef _Float16 f16x8 __attribute__((ext_vector_type(8)));
typedef float    f32x4 __attribute__((ext_vector_type(4)));

// ---------------------------------------------------------------------------
// K0: build Ybf — Y' transposed AND pre-blocked into MFMA B-fragment order.
//   Y'[n][c]: c 0..127 = teacher, 128 = y_sq, 129 = 1, 130..143 = 0.
//   Ybf[((ct*NB32 + nb)*64 + l)*8 + j] = Y'[nb*32 + (l>>4)*8 + j][ct*16 + (l&15)]
// Also zeroes the 8-float atomic accumulator block used by the fused epilogue.
// [byte-identical to round-7 build that ran]
// ---------------------------------------------------------------------------
__global__ __launch_bounds__(256) void build_ybf_k(const float* __restrict__ Y,
                                                   _Float16* __restrict__ Ybf,
                                                   float* __restrict__ accs) {
    __shared__ __align__(16) float Yl[64][132];
    __shared__ float ysql[64];
    const int t  = threadIdx.x;
    if (blockIdx.x == 0 && t < 8) accs[t] = 0.0f;   // zero sums + counter bits
    const int n0 = blockIdx.x * 64;
    const int nl = t >> 5;        // 0..7
    const int c4 = t & 31;
#pragma unroll
    for (int p = 0; p < 8; ++p) {
        const int n = p * 8 + nl;
        const float4 v = reinterpret_cast<const float4*>(Y + (size_t)(n0 + n) * C_DIM)[c4];
        reinterpret_cast<float4*>(Yl[n])[c4] = v;
        float sq = v.x * v.x + v.y * v.y + v.z * v.z + v.w * v.w;
#pragma unroll
        for (int m = 16; m >= 1; m >>= 1) sq += __shfl_xor(sq, m, 64);
        if (c4 == 0) ysql[n] = sq;
    }
    __syncthreads();
    // compose 1152 fragment-slots: (nb2, ct, l)
    for (int p = 0; p < 5; ++p) {
        const int s = t + p * 256;
        if (s < 1152) {
            const int nb2  = s / 576;
            const int r    = s % 576;
            const int ct   = r >> 6;
            const int l    = r & 63;
            const int quad = l >> 4, cl = l & 15;
            const int nloc = nb2 * 32 + quad * 8;
            f16x8 v;
            if (ct < 8) {
                const int c = ct * 16 + cl;
#pragma unroll
                for (int j = 0; j < 8; ++j) v[j] = (_Float16)Yl[nloc + j][c];
            } else if (cl == 0) {
#pragma unroll
                for (int j = 0; j < 8; ++j) v[j] = (_Float16)ysql[nloc + j];
            } else if (cl == 1) {
#pragma unroll
                for (int j = 0; j < 8; ++j) v[j] = (_Float16)1.0f;
            } else {
#pragma unroll
                for (int j = 0; j < 8; ++j) v[j] = (_Float16)0.0f;
            }
            const int nb = blockIdx.x * 2 + nb2;
            *reinterpret_cast<f16x8*>(Ybf + ((size_t)(ct * NB32 + nb) * 64 + l) * 8) = v;
        }
    }
}

// ---------------------------------------------------------------------------
// K0b: build Mt — M transposed into MFMA A-fragment order, fp16.
//   Mt[((fb*NB32 + nb)*64 + l)*8 + j] = (f16) M[nb*32 + (l>>4)*8 + j][fb*16 + (l&15)]
// Granularity theory (R1/R3/R4/R7 all pinned at 1.1-1.3 TB/s): every gemm
// variant touched M in 64-128B pieces of 8KB-strided rows -> ~20% DRAM/fabric
// efficiency. This pass reads M in 1KB-contiguous float4 runs (full speed),
// tiles 32n x 256fk through LDS, writes Mt coalesced (16B/lane contiguous).
// The gemm then streams Mt in perfect 1KB wave chunks.
// grid (512 nb, 2 fk-halves) x 256 thr; 4 fk-passes of 256 each.
// ---------------------------------------------------------------------------
__global__ __launch_bounds__(256) void build_mt_k(const float* __restrict__ M,
                                                  _Float16* __restrict__ Mt) {
    __shared__ __align__(16) float Lt[32][260];   // 33,280 B (pad 4 f32)
    const int t    = threadIdx.x;
    const int nb   = blockIdx.x;        // 0..511
    const int half = blockIdx.y;        // 0..1
    const int n0   = nb * 32;
#pragma unroll
    for (int pass = 0; pass < 4; ++pass) {
        const int fkbase = (half * 4 + pass) * 256;   // 0,256,...,1792
        __syncthreads();   // pass p-1 readers done before overwrite (p=0 harmless)
#pragma unroll
        for (int i = 0; i < 8; ++i) {
            const int idx = t + i * 256;    // 0..2047
            const int row = idx >> 6;       // 32 rows
            const int c4  = idx & 63;       // 64 float4/row
            const float4 v = reinterpret_cast<const float4*>(
                M + (size_t)(n0 + row) * FK + fkbase)[c4];
            reinterpret_cast<float4*>(&Lt[row][0])[c4] = v;
        }
        __syncthreads();
#pragma unroll
        for (int k2 = 0; k2 < 4; ++k2) {
            const int s   = t + k2 * 256;   // 0..1023
            const int fbl = s >> 6;         // 0..15
            const int l   = s & 63;
            const int quad = l >> 4, cl = l & 15;
            f16x8 v;
#pragma unroll
            for (int j = 0; j < 8; ++j)
                v[j] = (_Float16)Lt[quad * 8 + j][fbl * 16 + cl];
            const int fb = (half * 4 + pass) * 16 + fbl;   // 0..127
            *reinterpret_cast<f16x8*>(Mt + ((size_t)(fb * NB32 + nb) * 64 + l) * 8) = v;
        }
    }
}

// ---------------------------------------------------------------------------
// K1: split-K MFMA GEMM — round-7 structure (ran) with the A-path swapped:
// A-fragment is ONE contiguous f16x8 load from Mt (1 KB/wave/instr, HBM
// streaming), register double-buffered 2 steps ahead. A-LDS removed (LDS
// back to 36,864 B -> 4 blocks/CU); no f32->f16 converts in the loop; B
// staging / 2-barrier loop / LDS merge / CW-ordered wpart byte-identical
// to round-7.
// ---------------------------------------------------------------------------
__global__ __launch_bounds__(256) void gemm_k(const _Float16* __restrict__ Mt,
                                              const _Float16* __restrict__ Ybf,
                                              float* __restrict__ wpart,
                                              int cn) {
    __shared__ __align__(16) _Float16 Bb[2][2][9][512];   // [group][buf][ct] 36,864 B
    const int t    = threadIdx.x;
    const int fk0  = blockIdx.x * 32;
    const int ch   = blockIdx.y;
    const int w    = t >> 6;       // 0..3
    const int g    = w >> 1;       // n-group (0/1)
    const int wl   = w & 1;        // fk-half within group
    const int l    = t & 63;
    const int quad = l >> 4;
    const int cl   = l & 15;
    const int n0   = ch * cn + g * (cn >> 1);
    const int nb0  = n0 >> 5;
    const int steps = cn >> 6;     // per-group steps of 32 n (cn mult of 128)
    const int fb   = blockIdx.x * 2 + wl;   // A fragment block (16 fk)
    const _Float16* mtp = Mt + ((size_t)fb * NB32 * 64 + l) * 8;

    f32x4 acc[9] = {};
    f16x8 ar[2];

#define STAGE(s, par)                                                          \
    {                                                                          \
        const int nb_ = nb0 + (s);                                             \
        _Pragma("unroll")                                                      \
        for (int ct = wl; ct < 9; ct += 2) {                                   \
            const _Float16* g_ = Ybf + ((size_t)(ct * NB32 + nb_) * 64 + l) * 8; \
            __builtin_amdgcn_global_load_lds(                                  \
                (const __attribute__((address_space(1))) unsigned*)g_,         \
                (__attribute__((address_space(3))) unsigned*)&Bb[g][par][ct][0], \
                16, 0, 0);                                                     \
        }                                                                      \
    }
#define LOADA(buf, s)                                                          \
    ar[buf] = *reinterpret_cast<const f16x8*>(mtp + (size_t)(nb0 + (s)) * 512);

    STAGE(0, 0); LOADA(0, 0);
    STAGE(1, 1); LOADA(1, 1);

    for (int s = 0; s < steps; s += 2) {
        // ---- even step: buf 0 ----
        __syncthreads();                    // stage(s) landed in LDS
        {
            f16x8 bf[9];
#pragma unroll
            for (int ct = 0; ct < 9; ++ct)
                bf[ct] = *reinterpret_cast<const f16x8*>(&Bb[g][0][ct][l * 8]);
            const f16x8 af = ar[0];
            __syncthreads();                // all waves done reading buf0
            if (s + 2 < steps) { STAGE(s + 2, 0); LOADA(0, s + 2); }
#pragma unroll
            for (int ct = 0; ct < 9; ++ct)
                acc[ct] = __builtin_amdgcn_mfma_f32_16x16x32_f16(af, bf[ct], acc[ct], 0, 0, 0);
        }
        // ---- odd step: buf 1 ----
        __syncthreads();                    // stage(s+1) landed in LDS
        {
            f16x8 bf[9];
#pragma unroll
            for (int ct = 0; ct < 9; ++ct)
                bf[ct] = *reinterpret_cast<const f16x8*>(&Bb[g][1][ct][l * 8]);
            const f16x8 af = ar[1];
            __syncthreads();                // all waves done reading buf1
            if (s + 3 < steps) { STAGE(s + 3, 1); LOADA(1, s + 3); }
#pragma unroll
            for (int ct = 0; ct < 9; ++ct)
                acc[ct] = __builtin_amdgcn_mfma_f32_16x16x32_f16(af, bf[ct], acc[ct], 0, 0, 0);
        }
    }
#undef STAGE
#undef LOADA

    // ---- in-block merge of group 1 into group 0 (LDS scratch aliases Bb) ----
    float* scr = reinterpret_cast<float*>(&Bb[0][0][0][0]);   // [32 rows][144 c] f32
    if (g == 1) {
#pragma unroll
        for (int ct = 0; ct < 9; ++ct)
#pragma unroll
            for (int r = 0; r < 4; ++r)
                scr[(wl * 16 + quad * 4 + r) * 144 + ct * 16 + cl] = acc[ct][r];
    }
    __syncthreads();
    if (g == 0) {
        // D layout: col(c) = lane&15, row(fk) = quad*4 + reg
        float* wp = wpart + (size_t)ch * FK * CW;
#pragma unroll
        for (int ct = 0; ct < 9; ++ct) {
            const int c = ct * 16 + cl;
            if (c < CW) {
#pragma unroll
                for (int r = 0; r < 4; ++r) {
                    const int row = wl * 16 + quad * 4 + r;
                    const int fk  = fk0 + row;
                    wp[(size_t)fk * CW + c] = acc[ct][r] + scr[row * 144 + c];
                }
            }
        }
    }
}

// ---------------------------------------------------------------------------
// R1: chunk reduction wpart -> W. 528 blocks x 128 thr, 4-way ILP over chunks.
// [byte-identical to round-7]
// ---------------------------------------------------------------------------
__global__ __launch_bounds__(128) void reduce_w_k(const float* __restrict__ wpart,
                                                  float* __restrict__ W, int nchunk) {
    const int idx = blockIdx.x * 128 + threadIdx.x;   // float4 index, grid exact
    const float4* src = reinterpret_cast<const float4*>(wpart);
    const size_t cs = (size_t)FK * CW / 4;
    float4 s0 = make_float4(0.f, 0.f, 0.f, 0.f), s1 = s0, s2 = s0, s3 = s0;
    int ch = 0;
    for (; ch + 3 < nchunk; ch += 4) {
        const float4 a = src[idx + (size_t)(ch + 0) * cs];
        const float4 b = src[idx + (size_t)(ch + 1) * cs];
        const float4 c = src[idx + (size_t)(ch + 2) * cs];
        const float4 d = src[idx + (size_t)(ch + 3) * cs];
        s0.x += a.x; s0.y += a.y; s0.z += a.z; s0.w += a.w;
        s1.x += b.x; s1.y += b.y; s1.z += b.z; s1.w += b.w;
        s2.x += c.x; s2.y += c.y; s2.z += c.z; s2.w += c.w;
        s3.x += d.x; s3.y += d.y; s3.z += d.z; s3.w += d.w;
    }
    for (; ch < nchunk; ++ch) {
        const float4 a = src[idx + (size_t)ch * cs];
        s0.x += a.x; s0.y += a.y; s0.z += a.z; s0.w += a.w;
    }
    float4 r;
    r.x = (s0.x + s1.x) + (s2.x + s3.x);
    r.y = (s0.y + s1.y) + (s2.y + s3.y);
    r.z = (s0.z + s1.z) + (s2.z + s3.z);
    r.w = (s0.w + s1.w) + (s2.w + s3.w);
    reinterpret_cast<float4*>(W)[idx] = r;
}

// ---------------------------------------------------------------------------
// R2: per-feature epilogue on reduced W (CW row-major). wv identity, entropy,
// neighbor repulsion, strict-upper Gram; fused atomic final reduction.
// [byte-identical to round-7, ran with absmax 0]
// ---------------------------------------------------------------------------
__global__ __launch_bounds__(256) void epilogue_k(const float* __restrict__ W,
                                                  float* __restrict__ accs,
                                                  float* __restrict__ out) {
    __shared__ __align__(16) float Wl[32][CW];
    __shared__ float Bv[32], Binv[32], S1v[32], csq[32];
    __shared__ float scr[32][8];
    __shared__ float4 red4[256];
    const int t = threadIdx.x;
    const int f = blockIdx.x;

    for (int e = t; e < 32 * 33; e += 256) {
        const int k = e / 33, c4 = e % 33;
        reinterpret_cast<float4*>(Wl[k])[c4] =
            reinterpret_cast<const float4*>(W + (size_t)(f * 32 + k) * CW)[c4];
    }
    __syncthreads();
    if (t < 32) {
        const float B = Wl[t][129] + EPS_F;
        Bv[t] = B; Binv[t] = 1.0f / B; S1v[t] = Wl[t][128];
    }
    __syncthreads();
    {   // centroids in place + c_sq partials
        const int k = t >> 3, g = t & 7;
        const float ib = Binv[k];
        float s = 0.f;
        for (int c = g * 16; c < g * 16 + 16; ++c) {
            const float v = Wl[k][c] * ib;
            Wl[k][c] = v;
            s = fmaf(v, v, s);
        }
        scr[k][g] = s;
    }
    __syncthreads();
    if (t < 32) {
        float s = 0.f;
#pragma unroll
        for (int g = 0; g < 8; ++g) s += scr[t][g];
        csq[t] = s;
    }
    __syncthreads();

    float my_disp = 0.f, my_ent = 0.f, my_rep = 0.f, my_inter = 0.f;
    if (t < 32) {
        my_disp = (S1v[t] - csq[t] * (Bv[t] + EPS_F)) * Binv[t];
        const float p = Bv[t] * (1.0f / (float)N_PTS);
        my_ent = p * logf(p + EPS_F);
    }
    {   // neighbor repulsion
        const int pr = t >> 3, g = t & 7;
        float s = 0.f;
        if (pr < 31) {
            for (int c = g * 16; c < g * 16 + 16; ++c) {
                const float d = Wl[pr][c] - Wl[pr + 1][c];
                s = fmaf(d, d, s);
            }
        }
        __syncthreads();
        scr[pr][g] = s;
    }
    __syncthreads();
    if (t < 31) {
        float d = 0.f;
#pragma unroll
        for (int g = 0; g < 8; ++g) d += scr[t][g];
        my_rep = expf(-d);
    }
    // all-pairs inter (strict upper), float4 dots
#pragma unroll
    for (int s4 = 0; s4 < 4; ++s4) {
        const int slot = t + s4 * 256;
        const int k = slot >> 5, j = slot & 31;
        if (k < j) {
            float dot = 0.f;
            for (int c4 = 0; c4 < 32; ++c4) {
                const float4 a = reinterpret_cast<const float4*>(Wl[k])[c4];
                const float4 b = reinterpret_cast<const float4*>(Wl[j])[c4];
                dot = fmaf(a.x, b.x, dot); dot = fmaf(a.y, b.y, dot);
                dot = fmaf(a.z, b.z, dot); dot = fmaf(a.w, b.w, dot);
            }
            my_inter += expf(-(csq[k] + csq[j] - 2.0f * dot));
        }
    }
    red4[t] = make_float4(my_disp, my_ent, my_rep, my_inter);
    __syncthreads();
    for (int off = 128; off >= 1; off >>= 1) {
        if (t < off) {
            const float4 a = red4[t], b = red4[t + off];
            red4[t] = make_float4(a.x + b.x, a.y + b.y, a.z + b.z, a.w + b.w);
        }
        __syncthreads();
    }
    if (t == 0) {
        atomicAdd(accs + 0, red4[0].x);
        atomicAdd(accs + 1, red4[0].y);
        atomicAdd(accs + 2, red4[0].z);
        atomicAdd(accs + 3, red4[0].w);
        __threadfence();
        const unsigned prev = __hip_atomic_fetch_add(
            reinterpret_cast<unsigned*>(accs + 4), 1u,
            __ATOMIC_ACQ_REL, __HIP_MEMORY_SCOPE_AGENT);
        if (prev == (unsigned)(F_DIM - 1)) {
            const float disp = __hip_atomic_load(accs + 0, __ATOMIC_RELAXED, __HIP_MEMORY_SCOPE_AGENT);
            const float ent  = __hip_atomic_load(accs + 1, __ATOMIC_RELAXED, __HIP_MEMORY_SCOPE_AGENT);
            const float rep  = __hip_atomic_load(accs + 2, __ATOMIC_RELAXED, __HIP_MEMORY_SCOPE_AGENT);
            const float inter = __hip_atomic_load(accs + 3, __ATOMIC_RELAXED, __HIP_MEMORY_SCOPE_AGENT)
                                * (1.0f / (float)F_DIM);
            out[0] = disp + 0.1f * ent + 0.5f * rep + 0.3f * inter;
            out[1] = disp;
            out[2] = ent;
            out[3] = rep;
            out[4] = inter;
        }
    }
}

extern "C" void kernel_launch(void* const* d_in, const int* in_sizes, int n_in,
                              void* d_out, int out_size, void* d_ws, size_t ws_size,
                              hipStream_t stream) {
    const float* M = (const float*)d_in[0];   // (16384, 64, 32) fp32
    const float* Y = (const float*)d_in[1];   // (16384, 128) fp32
    float* out = (float*)d_out;               // 5 floats
    char*  ws  = (char*)d_ws;

    const size_t ybfBytes = (size_t)9 * NB32 * 64 * 8 * sizeof(_Float16);  // 4,718,592
    const size_t mtBytes  = (size_t)FK * N_PTS * sizeof(_Float16);         // 67,108,864
    const size_t wBytes   = (size_t)FK * CW * sizeof(float);               // 1,081,344

    _Float16* Ybf   = (_Float16*)ws;
    _Float16* Mt    = (_Float16*)(ws + ybfBytes);
    float*    W     = (float*)(ws + ybfBytes + mtBytes);
    float*    accs  = (float*)(ws + ybfBytes + mtBytes + wBytes);  // 4 sums + counter
    float*    wpart = (float*)(ws + ybfBytes + mtBytes + wBytes + 1024);

    // WS guard: halve nchunk until wpart fits (fill evidence: ws >= 512 MiB,
    // so nchunk=16 -> total ~90 MB fits comfortably; guard kept for safety).
    const size_t used = ybfBytes + mtBytes + wBytes + 1024;
    int nchunk = 16;
    while (nchunk > 1 && used + (size_t)nchunk * wBytes > ws_size) nchunk >>= 1;
    const int cn = N_PTS / nchunk;   // multiple of 128

    build_ybf_k<<<dim3(N_PTS / 64), dim3(256), 0, stream>>>(Y, Ybf, accs);
    build_mt_k<<<dim3(NB32, 2), dim3(256), 0, stream>>>(M, Mt);
    gemm_k<<<dim3(64, nchunk), dim3(256), 0, stream>>>(Mt, Ybf, wpart, cn);
    reduce_w_k<<<dim3(FK * CW / 4 / 128), dim3(128), 0, stream>>>(wpart, W, nchunk);
    epilogue_k<<<dim3(F_DIM), dim3(256), 0, stream>>>(W, accs, out);
}

// Round 9
// 236.174 us; speedup vs baseline: 1.0712x; 1.0712x over previous
//
#include <hip/hip_runtime.h>
#include <math.h>

#define N_PTS   16384
#define F_DIM   64
#define K_BINS  32
#define C_DIM   128
#define FK      2048      // F*K
#define NB32    (N_PTS / 32)   // 512 n-blocks of 32
#define CW      132       // W row stride: [w0..w127, S1, B, pad0, pad0]
#define EPS_F   1e-8f

typedef _Float16 f16x8 __attribute__((ext_vector_type(8)));
typedef float    f32x4 __attribute__((ext_vector_type(4)));

// ---------------------------------------------------------------------------
// K0: build Ybf — Y' transposed AND pre-blocked into MFMA B-fragment order.
//   Y'[n][c]: c 0..127 = teacher, 128 = y_sq, 129 = 1, 130..143 = 0.
//   Ybf[((ct*NB32 + nb)*64 + l)*8 + j] = Y'[nb*32 + (l>>4)*8 + j][ct*16 + (l&15)]
// Also zeroes the 8-float atomic accumulator block used by the fused epilogue.
// [byte-identical to R7/R8 builds that ran, absmax 0]
// ---------------------------------------------------------------------------
__global__ __launch_bounds__(256) void build_ybf_k(const float* __restrict__ Y,
                                                   _Float16* __restrict__ Ybf,
                                                   float* __restrict__ accs) {
    __shared__ __align__(16) float Yl[64][132];
    __shared__ float ysql[64];
    const int t  = threadIdx.x;
    if (blockIdx.x == 0 && t < 8) accs[t] = 0.0f;   // zero sums + counter bits
    const int n0 = blockIdx.x * 64;
    const int nl = t >> 5;        // 0..7
    const int c4 = t & 31;
#pragma unroll
    for (int p = 0; p < 8; ++p) {
        const int n = p * 8 + nl;
        const float4 v = reinterpret_cast<const float4*>(Y + (size_t)(n0 + n) * C_DIM)[c4];
        reinterpret_cast<float4*>(Yl[n])[c4] = v;
        float sq = v.x * v.x + v.y * v.y + v.z * v.z + v.w * v.w;
#pragma unroll
        for (int m = 16; m >= 1; m >>= 1) sq += __shfl_xor(sq, m, 64);
        if (c4 == 0) ysql[n] = sq;
    }
    __syncthreads();
    // compose 1152 fragment-slots: (nb2, ct, l)
    for (int p = 0; p < 5; ++p) {
        const int s = t + p * 256;
        if (s < 1152) {
            const int nb2  = s / 576;
            const int r    = s % 576;
            const int ct   = r >> 6;
            const int l    = r & 63;
            const int quad = l >> 4, cl = l & 15;
            const int nloc = nb2 * 32 + quad * 8;
            f16x8 v;
            if (ct < 8) {
                const int c = ct * 16 + cl;
#pragma unroll
                for (int j = 0; j < 8; ++j) v[j] = (_Float16)Yl[nloc + j][c];
            } else if (cl == 0) {
#pragma unroll
                for (int j = 0; j < 8; ++j) v[j] = (_Float16)ysql[nloc + j];
            } else if (cl == 1) {
#pragma unroll
                for (int j = 0; j < 8; ++j) v[j] = (_Float16)1.0f;
            } else {
#pragma unroll
                for (int j = 0; j < 8; ++j) v[j] = (_Float16)0.0f;
            }
            const int nb = blockIdx.x * 2 + nb2;
            *reinterpret_cast<f16x8*>(Ybf + ((size_t)(ct * NB32 + nb) * 64 + l) * 8) = v;
        }
    }
}

// ---------------------------------------------------------------------------
// K1: split-K MFMA GEMM — WIDE-TILE direct-M version (no transpose pass).
// Evidence R1/R3/R4/R7: any fk-tile-32 reader touches M in 64-128B granules
// -> pinned at 1.1-1.3 TB/s regardless of schedule. R8's pre-transpose paid
// its own cost back in extra traffic (mt+gemm ~= old gemm). This version
// reads M DIRECTLY but at fk-tile 128: each A-stage wave-load is 1 KB
// covering two full 512B-contiguous row segments (8 sequential cache lines)
// -> DRAM-efficient, zero extra traffic, M read exactly once.
//   A-tile: At[32 n][128 fk] f32 via global_load_lds dwordx4 (linear dest:
//     lane l -> row w*8+i*2+(l>>5), cols (l&31)*4.. ; matches gA source).
//   A-frag: 16 ds_read_b32 + cvt per step (4-way conflict, ~150cyc, noise).
//   Per wave: 2 fk-frags x 9 ct MFMA, acc[2][9].
// Grid 16 x nchunk(64) = 1024 blocks, LDS 50 KB -> 3 blocks/CU.
// B-path / 2-barrier double-buffer / CW-ordered wpart: verified R0/R7 code.
// ---------------------------------------------------------------------------
__global__ __launch_bounds__(256, 3) void gemm_k(const float* __restrict__ M,
                                                 const _Float16* __restrict__ Ybf,
                                                 float* __restrict__ wpart,
                                                 int cn) {
    __shared__ __align__(16) float    At[2][32][128];   // 2 x 16 KB
    __shared__ __align__(16) _Float16 Bb[2][9][512];    // 2 x 9 KB
    const int t    = threadIdx.x;
    const int fk0  = blockIdx.x * 128;
    const int ch   = blockIdx.y;
    const int w    = t >> 6;       // wave 0..3, owns fk0 + w*32 .. +31
    const int l    = t & 63;
    const int quad = l >> 4;
    const int cl   = l & 15;
    const int n0   = ch * cn;
    const int nb0  = n0 >> 5;
    const int steps = cn >> 5;     // even (cn multiple of 64)

    f32x4 acc[2][9] = {};

#define STAGE(s, par)                                                          \
    {                                                                          \
        const int nb_ = nb0 + (s);                                             \
        _Pragma("unroll")                                                      \
        for (int ct = w; ct < 9; ct += 4) {                                    \
            const _Float16* g_ = Ybf + ((size_t)(ct * NB32 + nb_) * 64 + l) * 8; \
            __builtin_amdgcn_global_load_lds(                                  \
                (const __attribute__((address_space(1))) unsigned*)g_,         \
                (__attribute__((address_space(3))) unsigned*)&Bb[par][ct][0],  \
                16, 0, 0);                                                     \
        }                                                                      \
        _Pragma("unroll")                                                      \
        for (int i = 0; i < 4; ++i) {                                          \
            const int row = w * 8 + i * 2 + (l >> 5);                          \
            const float* gA = M + (size_t)(n0 + (s) * 32 + row) * FK           \
                              + fk0 + (l & 31) * 4;                            \
            __builtin_amdgcn_global_load_lds(                                  \
                (const __attribute__((address_space(1))) unsigned*)gA,         \
                (__attribute__((address_space(3))) unsigned*)&At[par][w * 8 + i * 2][0], \
                16, 0, 0);                                                     \
        }                                                                      \
    }

    STAGE(0, 0);
    STAGE(1, 1);

    for (int s = 0; s < steps; s += 2) {
        // ---- even step: buf 0 ----
        __syncthreads();                     // stage(s) landed
        {
            f16x8 bf[9];
#pragma unroll
            for (int ct = 0; ct < 9; ++ct)
                bf[ct] = *reinterpret_cast<const f16x8*>(&Bb[0][ct][l * 8]);
            f16x8 af0, af1;
#pragma unroll
            for (int j = 0; j < 8; ++j) {
                af0[j] = (_Float16)At[0][quad * 8 + j][w * 32 + cl];
                af1[j] = (_Float16)At[0][quad * 8 + j][w * 32 + 16 + cl];
            }
            __syncthreads();                 // all waves done reading buf0
            if (s + 2 < steps) STAGE(s + 2, 0);
#pragma unroll
            for (int ct = 0; ct < 9; ++ct) {
                acc[0][ct] = __builtin_amdgcn_mfma_f32_16x16x32_f16(af0, bf[ct], acc[0][ct], 0, 0, 0);
                acc[1][ct] = __builtin_amdgcn_mfma_f32_16x16x32_f16(af1, bf[ct], acc[1][ct], 0, 0, 0);
            }
        }
        // ---- odd step: buf 1 ----
        __syncthreads();                     // stage(s+1) landed
        {
            f16x8 bf[9];
#pragma unroll
            for (int ct = 0; ct < 9; ++ct)
                bf[ct] = *reinterpret_cast<const f16x8*>(&Bb[1][ct][l * 8]);
            f16x8 af0, af1;
#pragma unroll
            for (int j = 0; j < 8; ++j) {
                af0[j] = (_Float16)At[1][quad * 8 + j][w * 32 + cl];
                af1[j] = (_Float16)At[1][quad * 8 + j][w * 32 + 16 + cl];
            }
            __syncthreads();                 // all waves done reading buf1
            if (s + 3 < steps) STAGE(s + 3, 1);
#pragma unroll
            for (int ct = 0; ct < 9; ++ct) {
                acc[0][ct] = __builtin_amdgcn_mfma_f32_16x16x32_f16(af0, bf[ct], acc[0][ct], 0, 0, 0);
                acc[1][ct] = __builtin_amdgcn_mfma_f32_16x16x32_f16(af1, bf[ct], acc[1][ct], 0, 0, 0);
            }
        }
    }
#undef STAGE

    // ---- CW-ordered C-write (verified R0 mapping) ----
    // D layout: col(c) = lane&15, row(fk within frag) = quad*4 + reg.
    float* wp = wpart + (size_t)ch * FK * CW;
#pragma unroll
    for (int f = 0; f < 2; ++f) {
#pragma unroll
        for (int ct = 0; ct < 9; ++ct) {
            const int c = ct * 16 + cl;
            if (c < CW) {
#pragma unroll
                for (int r = 0; r < 4; ++r) {
                    const int fk = fk0 + w * 32 + f * 16 + quad * 4 + r;
                    wp[(size_t)fk * CW + c] = acc[f][ct][r];
                }
            }
        }
    }
}

// ---------------------------------------------------------------------------
// R1: chunk reduction wpart -> W. 528 blocks x 128 thr, 4-way ILP over chunks.
// [verified R0/R7 code; handles any nchunk]
// ---------------------------------------------------------------------------
__global__ __launch_bounds__(128) void reduce_w_k(const float* __restrict__ wpart,
                                                  float* __restrict__ W, int nchunk) {
    const int idx = blockIdx.x * 128 + threadIdx.x;   // float4 index, grid exact
    const float4* src = reinterpret_cast<const float4*>(wpart);
    const size_t cs = (size_t)FK * CW / 4;
    float4 s0 = make_float4(0.f, 0.f, 0.f, 0.f), s1 = s0, s2 = s0, s3 = s0;
    int ch = 0;
    for (; ch + 3 < nchunk; ch += 4) {
        const float4 a = src[idx + (size_t)(ch + 0) * cs];
        const float4 b = src[idx + (size_t)(ch + 1) * cs];
        const float4 c = src[idx + (size_t)(ch + 2) * cs];
        const float4 d = src[idx + (size_t)(ch + 3) * cs];
        s0.x += a.x; s0.y += a.y; s0.z += a.z; s0.w += a.w;
        s1.x += b.x; s1.y += b.y; s1.z += b.z; s1.w += b.w;
        s2.x += c.x; s2.y += c.y; s2.z += c.z; s2.w += c.w;
        s3.x += d.x; s3.y += d.y; s3.z += d.z; s3.w += d.w;
    }
    for (; ch < nchunk; ++ch) {
        const float4 a = src[idx + (size_t)ch * cs];
        s0.x += a.x; s0.y += a.y; s0.z += a.z; s0.w += a.w;
    }
    float4 r;
    r.x = (s0.x + s1.x) + (s2.x + s3.x);
    r.y = (s0.y + s1.y) + (s2.y + s3.y);
    r.z = (s0.z + s1.z) + (s2.z + s3.z);
    r.w = (s0.w + s1.w) + (s2.w + s3.w);
    reinterpret_cast<float4*>(W)[idx] = r;
}

// ---------------------------------------------------------------------------
// R2: per-feature epilogue on reduced W (CW row-major). wv identity, entropy,
// neighbor repulsion, strict-upper Gram; fused atomic final reduction.
// [verified R0/R7 code, absmax 0]
// ---------------------------------------------------------------------------
__global__ __launch_bounds__(256) void epilogue_k(const float* __restrict__ W,
                                                  float* __restrict__ accs,
                                                  float* __restrict__ out) {
    __shared__ __align__(16) float Wl[32][CW];
    __shared__ float Bv[32], Binv[32], S1v[32], csq[32];
    __shared__ float scr[32][8];
    __shared__ float4 red4[256];
    const int t = threadIdx.x;
    const int f = blockIdx.x;

    for (int e = t; e < 32 * 33; e += 256) {
        const int k = e / 33, c4 = e % 33;
        reinterpret_cast<float4*>(Wl[k])[c4] =
            reinterpret_cast<const float4*>(W + (size_t)(f * 32 + k) * CW)[c4];
    }
    __syncthreads();
    if (t < 32) {
        const float B = Wl[t][129] + EPS_F;
        Bv[t] = B; Binv[t] = 1.0f / B; S1v[t] = Wl[t][128];
    }
    __syncthreads();
    {   // centroids in place + c_sq partials
        const int k = t >> 3, g = t & 7;
        const float ib = Binv[k];
        float s = 0.f;
        for (int c = g * 16; c < g * 16 + 16; ++c) {
            const float v = Wl[k][c] * ib;
            Wl[k][c] = v;
            s = fmaf(v, v, s);
        }
        scr[k][g] = s;
    }
    __syncthreads();
    if (t < 32) {
        float s = 0.f;
#pragma unroll
        for (int g = 0; g < 8; ++g) s += scr[t][g];
        csq[t] = s;
    }
    __syncthreads();

    float my_disp = 0.f, my_ent = 0.f, my_rep = 0.f, my_inter = 0.f;
    if (t < 32) {
        my_disp = (S1v[t] - csq[t] * (Bv[t] + EPS_F)) * Binv[t];
        const float p = Bv[t] * (1.0f / (float)N_PTS);
        my_ent = p * logf(p + EPS_F);
    }
    {   // neighbor repulsion
        const int pr = t >> 3, g = t & 7;
        float s = 0.f;
        if (pr < 31) {
            for (int c = g * 16; c < g * 16 + 16; ++c) {
                const float d = Wl[pr][c] - Wl[pr + 1][c];
                s = fmaf(d, d, s);
            }
        }
        __syncthreads();
        scr[pr][g] = s;
    }
    __syncthreads();
    if (t < 31) {
        float d = 0.f;
#pragma unroll
        for (int g = 0; g < 8; ++g) d += scr[t][g];
        my_rep = expf(-d);
    }
    // all-pairs inter (strict upper), float4 dots
#pragma unroll
    for (int s4 = 0; s4 < 4; ++s4) {
        const int slot = t + s4 * 256;
        const int k = slot >> 5, j = slot & 31;
        if (k < j) {
            float dot = 0.f;
            for (int c4 = 0; c4 < 32; ++c4) {
                const float4 a = reinterpret_cast<const float4*>(Wl[k])[c4];
                const float4 b = reinterpret_cast<const float4*>(Wl[j])[c4];
                dot = fmaf(a.x, b.x, dot); dot = fmaf(a.y, b.y, dot);
                dot = fmaf(a.z, b.z, dot); dot = fmaf(a.w, b.w, dot);
            }
            my_inter += expf(-(csq[k] + csq[j] - 2.0f * dot));
        }
    }
    red4[t] = make_float4(my_disp, my_ent, my_rep, my_inter);
    __syncthreads();
    for (int off = 128; off >= 1; off >>= 1) {
        if (t < off) {
            const float4 a = red4[t], b = red4[t + off];
            red4[t] = make_float4(a.x + b.x, a.y + b.y, a.z + b.z, a.w + b.w);
        }
        __syncthreads();
    }
    if (t == 0) {
        atomicAdd(accs + 0, red4[0].x);
        atomicAdd(accs + 1, red4[0].y);
        atomicAdd(accs + 2, red4[0].z);
        atomicAdd(accs + 3, red4[0].w);
        __threadfence();
        const unsigned prev = __hip_atomic_fetch_add(
            reinterpret_cast<unsigned*>(accs + 4), 1u,
            __ATOMIC_ACQ_REL, __HIP_MEMORY_SCOPE_AGENT);
        if (prev == (unsigned)(F_DIM - 1)) {
            const float disp = __hip_atomic_load(accs + 0, __ATOMIC_RELAXED, __HIP_MEMORY_SCOPE_AGENT);
            const float ent  = __hip_atomic_load(accs + 1, __ATOMIC_RELAXED, __HIP_MEMORY_SCOPE_AGENT);
            const float rep  = __hip_atomic_load(accs + 2, __ATOMIC_RELAXED, __HIP_MEMORY_SCOPE_AGENT);
            const float inter = __hip_atomic_load(accs + 3, __ATOMIC_RELAXED, __HIP_MEMORY_SCOPE_AGENT)
                                * (1.0f / (float)F_DIM);
            out[0] = disp + 0.1f * ent + 0.5f * rep + 0.3f * inter;
            out[1] = disp;
            out[2] = ent;
            out[3] = rep;
            out[4] = inter;
        }
    }
}

extern "C" void kernel_launch(void* const* d_in, const int* in_sizes, int n_in,
                              void* d_out, int out_size, void* d_ws, size_t ws_size,
                              hipStream_t stream) {
    const float* M = (const float*)d_in[0];   // (16384, 64, 32) fp32
    const float* Y = (const float*)d_in[1];   // (16384, 128) fp32
    float* out = (float*)d_out;               // 5 floats
    char*  ws  = (char*)d_ws;

    const size_t ybfBytes = (size_t)9 * NB32 * 64 * 8 * sizeof(_Float16);  // 4,718,592
    const size_t wBytes   = (size_t)FK * CW * sizeof(float);               // 1,081,344

    _Float16* Ybf   = (_Float16*)ws;
    float*    W     = (float*)(ws + ybfBytes);
    float*    accs  = (float*)(ws + ybfBytes + wBytes);        // 4 sums + counter
    float*    wpart = (float*)(ws + ybfBytes + wBytes + 1024);

    // WS guard: halve nchunk until wpart fits. nchunk=64 -> ~75 MB total
    // (fills show ws >= 512 MiB, so this should hold at 64).
    const size_t used = ybfBytes + wBytes + 1024;
    int nchunk = 64;
    while (nchunk > 1 && used + (size_t)nchunk * wBytes > ws_size) nchunk >>= 1;
    const int cn = N_PTS / nchunk;   // 256 at nchunk=64; multiple of 64

    build_ybf_k<<<dim3(N_PTS / 64), dim3(256), 0, stream>>>(Y, Ybf, accs);
    gemm_k<<<dim3(16, nchunk), dim3(256), 0, stream>>>(M, Ybf, wpart, cn);
    reduce_w_k<<<dim3(FK * CW / 4 / 128), dim3(128), 0, stream>>>(wpart, W, nchunk);
    epilogue_k<<<dim3(F_DIM), dim3(256), 0, stream>>>(W, accs, out);
}

// Round 10
// 226.483 us; speedup vs baseline: 1.1170x; 1.0428x over previous
//
#include <hip/hip_runtime.h>
#include <math.h>

#define N_PTS   16384
#define F_DIM   64
#define K_BINS  32
#define C_DIM   128
#define FK      2048      // F*K
#define NB32    (N_PTS / 32)   // 512 n-blocks of 32
#define CW      132       // W row stride: [w0..w127, S1, B, pad0, pad0]
#define EPS_F   1e-8f

typedef _Float16 f16x8 __attribute__((ext_vector_type(8)));
typedef float    f32x4 __attribute__((ext_vector_type(4)));

// ---------------------------------------------------------------------------
// K0: build Ybf — Y' transposed AND pre-blocked into MFMA B-fragment order.
//   Y'[n][c]: c 0..127 = teacher, 128 = y_sq, 129 = 1, 130..143 = 0.
//   Ybf[((ct*NB32 + nb)*64 + l)*8 + j] = Y'[nb*32 + (l>>4)*8 + j][ct*16 + (l&15)]
// Also zeroes the 8-float atomic accumulator block used by the fused epilogue.
// [byte-identical to R7/R8/R9 builds that ran, absmax 0]
// ---------------------------------------------------------------------------
__global__ __launch_bounds__(256) void build_ybf_k(const float* __restrict__ Y,
                                                   _Float16* __restrict__ Ybf,
                                                   float* __restrict__ accs) {
    __shared__ __align__(16) float Yl[64][132];
    __shared__ float ysql[64];
    const int t  = threadIdx.x;
    if (blockIdx.x == 0 && t < 8) accs[t] = 0.0f;   // zero sums + counter bits
    const int n0 = blockIdx.x * 64;
    const int nl = t >> 5;        // 0..7
    const int c4 = t & 31;
#pragma unroll
    for (int p = 0; p < 8; ++p) {
        const int n = p * 8 + nl;
        const float4 v = reinterpret_cast<const float4*>(Y + (size_t)(n0 + n) * C_DIM)[c4];
        reinterpret_cast<float4*>(Yl[n])[c4] = v;
        float sq = v.x * v.x + v.y * v.y + v.z * v.z + v.w * v.w;
#pragma unroll
        for (int m = 16; m >= 1; m >>= 1) sq += __shfl_xor(sq, m, 64);
        if (c4 == 0) ysql[n] = sq;
    }
    __syncthreads();
    // compose 1152 fragment-slots: (nb2, ct, l)
    for (int p = 0; p < 5; ++p) {
        const int s = t + p * 256;
        if (s < 1152) {
            const int nb2  = s / 576;
            const int r    = s % 576;
            const int ct   = r >> 6;
            const int l    = r & 63;
            const int quad = l >> 4, cl = l & 15;
            const int nloc = nb2 * 32 + quad * 8;
            f16x8 v;
            if (ct < 8) {
                const int c = ct * 16 + cl;
#pragma unroll
                for (int j = 0; j < 8; ++j) v[j] = (_Float16)Yl[nloc + j][c];
            } else if (cl == 0) {
#pragma unroll
                for (int j = 0; j < 8; ++j) v[j] = (_Float16)ysql[nloc + j];
            } else if (cl == 1) {
#pragma unroll
                for (int j = 0; j < 8; ++j) v[j] = (_Float16)1.0f;
            } else {
#pragma unroll
                for (int j = 0; j < 8; ++j) v[j] = (_Float16)0.0f;
            }
            const int nb = blockIdx.x * 2 + nb2;
            *reinterpret_cast<f16x8*>(Ybf + ((size_t)(ct * NB32 + nb) * 64 + l) * 8) = v;
        }
    }
}

// ---------------------------------------------------------------------------
// K1: split-K MFMA GEMM — R9 wide-tile kernel (ran, absmax 0) with TRAFFIC
// minimization. Fabric-traffic model (fits R1/R3/R7/R9): gemm time ~=
// (B-rereads + A + wpart) / ~5.5 TB/s. Changes vs R9:
//   (a) nchunk 64->32 (wpart traffic halves),
//   (b) XCD co-location: 1D grid, decode so all 16 fk-siblings of a chunk
//       land on ONE XCD (dispatch: block i -> XCD i%8) -> each chunk's
//       147 KB B-slice is HBM-fetched once per XCD, not ~8x.
//       B HBM traffic 37.6 -> ~4.7 MB. Perf heuristic only (correctness
//       never depends on the mapping); bijective for nchunk mult of 8,
//       linear fallback otherwise.
// Compute structure byte-identical to R9: fk-tile 128, A staged via
// global_load_lds dwordx4 (512B-contiguous row segments), 2-barrier
// double-buffer, acc[2][9], CW-ordered wpart.
// ---------------------------------------------------------------------------
__global__ __launch_bounds__(256, 3) void gemm_k(const float* __restrict__ M,
                                                 const _Float16* __restrict__ Ybf,
                                                 float* __restrict__ wpart,
                                                 int cn, int nchunk) {
    __shared__ __align__(16) float    At[2][32][128];   // 2 x 16 KB
    __shared__ __align__(16) _Float16 Bb[2][9][512];    // 2 x 9 KB
    const int t  = threadIdx.x;
    // ---- XCD-swizzled block decode ----
    const int b = blockIdx.x;            // 0 .. 16*nchunk-1
    int bx, ch;
    if ((nchunk & 7) == 0) {
        const int xcd  = b & 7;
        const int slot = b >> 3;
        bx = slot & 15;
        ch = xcd + 8 * (slot >> 4);
    } else {
        bx = b & 15;
        ch = b >> 4;
    }
    const int fk0  = bx * 128;
    const int w    = t >> 6;       // wave 0..3, owns fk0 + w*32 .. +31
    const int l    = t & 63;
    const int quad = l >> 4;
    const int cl   = l & 15;
    const int n0   = ch * cn;
    const int nb0  = n0 >> 5;
    const int steps = cn >> 5;     // even (cn multiple of 64)

    f32x4 acc[2][9] = {};

#define STAGE(s, par)                                                          \
    {                                                                          \
        const int nb_ = nb0 + (s);                                             \
        _Pragma("unroll")                                                      \
        for (int ct = w; ct < 9; ct += 4) {                                    \
            const _Float16* g_ = Ybf + ((size_t)(ct * NB32 + nb_) * 64 + l) * 8; \
            __builtin_amdgcn_global_load_lds(                                  \
                (const __attribute__((address_space(1))) unsigned*)g_,         \
                (__attribute__((address_space(3))) unsigned*)&Bb[par][ct][0],  \
                16, 0, 0);                                                     \
        }                                                                      \
        _Pragma("unroll")                                                      \
        for (int i = 0; i < 4; ++i) {                                          \
            const int row = w * 8 + i * 2 + (l >> 5);                          \
            const float* gA = M + (size_t)(n0 + (s) * 32 + row) * FK           \
                              + fk0 + (l & 31) * 4;                            \
            __builtin_amdgcn_global_load_lds(                                  \
                (const __attribute__((address_space(1))) unsigned*)gA,         \
                (__attribute__((address_space(3))) unsigned*)&At[par][w * 8 + i * 2][0], \
                16, 0, 0);                                                     \
        }                                                                      \
    }

    STAGE(0, 0);
    STAGE(1, 1);

    for (int s = 0; s < steps; s += 2) {
        // ---- even step: buf 0 ----
        __syncthreads();                     // stage(s) landed
        {
            f16x8 bf[9];
#pragma unroll
            for (int ct = 0; ct < 9; ++ct)
                bf[ct] = *reinterpret_cast<const f16x8*>(&Bb[0][ct][l * 8]);
            f16x8 af0, af1;
#pragma unroll
            for (int j = 0; j < 8; ++j) {
                af0[j] = (_Float16)At[0][quad * 8 + j][w * 32 + cl];
                af1[j] = (_Float16)At[0][quad * 8 + j][w * 32 + 16 + cl];
            }
            __syncthreads();                 // all waves done reading buf0
            if (s + 2 < steps) STAGE(s + 2, 0);
#pragma unroll
            for (int ct = 0; ct < 9; ++ct) {
                acc[0][ct] = __builtin_amdgcn_mfma_f32_16x16x32_f16(af0, bf[ct], acc[0][ct], 0, 0, 0);
                acc[1][ct] = __builtin_amdgcn_mfma_f32_16x16x32_f16(af1, bf[ct], acc[1][ct], 0, 0, 0);
            }
        }
        // ---- odd step: buf 1 ----
        __syncthreads();                     // stage(s+1) landed
        {
            f16x8 bf[9];
#pragma unroll
            for (int ct = 0; ct < 9; ++ct)
                bf[ct] = *reinterpret_cast<const f16x8*>(&Bb[1][ct][l * 8]);
            f16x8 af0, af1;
#pragma unroll
            for (int j = 0; j < 8; ++j) {
                af0[j] = (_Float16)At[1][quad * 8 + j][w * 32 + cl];
                af1[j] = (_Float16)At[1][quad * 8 + j][w * 32 + 16 + cl];
            }
            __syncthreads();                 // all waves done reading buf1
            if (s + 3 < steps) STAGE(s + 3, 1);
#pragma unroll
            for (int ct = 0; ct < 9; ++ct) {
                acc[0][ct] = __builtin_amdgcn_mfma_f32_16x16x32_f16(af0, bf[ct], acc[0][ct], 0, 0, 0);
                acc[1][ct] = __builtin_amdgcn_mfma_f32_16x16x32_f16(af1, bf[ct], acc[1][ct], 0, 0, 0);
            }
        }
    }
#undef STAGE

    // ---- CW-ordered C-write (verified R0/R9 mapping) ----
    // D layout: col(c) = lane&15, row(fk within frag) = quad*4 + reg.
    float* wp = wpart + (size_t)ch * FK * CW;
#pragma unroll
    for (int f = 0; f < 2; ++f) {
#pragma unroll
        for (int ct = 0; ct < 9; ++ct) {
            const int c = ct * 16 + cl;
            if (c < CW) {
#pragma unroll
                for (int r = 0; r < 4; ++r) {
                    const int fk = fk0 + w * 32 + f * 16 + quad * 4 + r;
                    wp[(size_t)fk * CW + c] = acc[f][ct][r];
                }
            }
        }
    }
}

// ---------------------------------------------------------------------------
// R1: chunk reduction wpart -> W. 528 blocks x 128 thr, 4-way ILP over chunks.
// [verified R0/R7/R9 code; handles any nchunk]
// ---------------------------------------------------------------------------
__global__ __launch_bounds__(128) void reduce_w_k(const float* __restrict__ wpart,
                                                  float* __restrict__ W, int nchunk) {
    const int idx = blockIdx.x * 128 + threadIdx.x;   // float4 index, grid exact
    const float4* src = reinterpret_cast<const float4*>(wpart);
    const size_t cs = (size_t)FK * CW / 4;
    float4 s0 = make_float4(0.f, 0.f, 0.f, 0.f), s1 = s0, s2 = s0, s3 = s0;
    int ch = 0;
    for (; ch + 3 < nchunk; ch += 4) {
        const float4 a = src[idx + (size_t)(ch + 0) * cs];
        const float4 b = src[idx + (size_t)(ch + 1) * cs];
        const float4 c = src[idx + (size_t)(ch + 2) * cs];
        const float4 d = src[idx + (size_t)(ch + 3) * cs];
        s0.x += a.x; s0.y += a.y; s0.z += a.z; s0.w += a.w;
        s1.x += b.x; s1.y += b.y; s1.z += b.z; s1.w += b.w;
        s2.x += c.x; s2.y += c.y; s2.z += c.z; s2.w += c.w;
        s3.x += d.x; s3.y += d.y; s3.z += d.z; s3.w += d.w;
    }
    for (; ch < nchunk; ++ch) {
        const float4 a = src[idx + (size_t)ch * cs];
        s0.x += a.x; s0.y += a.y; s0.z += a.z; s0.w += a.w;
    }
    float4 r;
    r.x = (s0.x + s1.x) + (s2.x + s3.x);
    r.y = (s0.y + s1.y) + (s2.y + s3.y);
    r.z = (s0.z + s1.z) + (s2.z + s3.z);
    r.w = (s0.w + s1.w) + (s2.w + s3.w);
    reinterpret_cast<float4*>(W)[idx] = r;
}

// ---------------------------------------------------------------------------
// R2: per-feature epilogue on reduced W (CW row-major). wv identity, entropy,
// neighbor repulsion, strict-upper Gram; fused atomic final reduction.
// [verified R0/R7/R9 code, absmax 0]
// ---------------------------------------------------------------------------
__global__ __launch_bounds__(256) void epilogue_k(const float* __restrict__ W,
                                                  float* __restrict__ accs,
                                                  float* __restrict__ out) {
    __shared__ __align__(16) float Wl[32][CW];
    __shared__ float Bv[32], Binv[32], S1v[32], csq[32];
    __shared__ float scr[32][8];
    __shared__ float4 red4[256];
    const int t = threadIdx.x;
    const int f = blockIdx.x;

    for (int e = t; e < 32 * 33; e += 256) {
        const int k = e / 33, c4 = e % 33;
        reinterpret_cast<float4*>(Wl[k])[c4] =
            reinterpret_cast<const float4*>(W + (size_t)(f * 32 + k) * CW)[c4];
    }
    __syncthreads();
    if (t < 32) {
        const float B = Wl[t][129] + EPS_F;
        Bv[t] = B; Binv[t] = 1.0f / B; S1v[t] = Wl[t][128];
    }
    __syncthreads();
    {   // centroids in place + c_sq partials
        const int k = t >> 3, g = t & 7;
        const float ib = Binv[k];
        float s = 0.f;
        for (int c = g * 16; c < g * 16 + 16; ++c) {
            const float v = Wl[k][c] * ib;
            Wl[k][c] = v;
            s = fmaf(v, v, s);
        }
        scr[k][g] = s;
    }
    __syncthreads();
    if (t < 32) {
        float s = 0.f;
#pragma unroll
        for (int g = 0; g < 8; ++g) s += scr[t][g];
        csq[t] = s;
    }
    __syncthreads();

    float my_disp = 0.f, my_ent = 0.f, my_rep = 0.f, my_inter = 0.f;
    if (t < 32) {
        my_disp = (S1v[t] - csq[t] * (Bv[t] + EPS_F)) * Binv[t];
        const float p = Bv[t] * (1.0f / (float)N_PTS);
        my_ent = p * logf(p + EPS_F);
    }
    {   // neighbor repulsion
        const int pr = t >> 3, g = t & 7;
        float s = 0.f;
        if (pr < 31) {
            for (int c = g * 16; c < g * 16 + 16; ++c) {
                const float d = Wl[pr][c] - Wl[pr + 1][c];
                s = fmaf(d, d, s);
            }
        }
        __syncthreads();
        scr[pr][g] = s;
    }
    __syncthreads();
    if (t < 31) {
        float d = 0.f;
#pragma unroll
        for (int g = 0; g < 8; ++g) d += scr[t][g];
        my_rep = expf(-d);
    }
    // all-pairs inter (strict upper), float4 dots
#pragma unroll
    for (int s4 = 0; s4 < 4; ++s4) {
        const int slot = t + s4 * 256;
        const int k = slot >> 5, j = slot & 31;
        if (k < j) {
            float dot = 0.f;
            for (int c4 = 0; c4 < 32; ++c4) {
                const float4 a = reinterpret_cast<const float4*>(Wl[k])[c4];
                const float4 b = reinterpret_cast<const float4*>(Wl[j])[c4];
                dot = fmaf(a.x, b.x, dot); dot = fmaf(a.y, b.y, dot);
                dot = fmaf(a.z, b.z, dot); dot = fmaf(a.w, b.w, dot);
            }
            my_inter += expf(-(csq[k] + csq[j] - 2.0f * dot));
        }
    }
    red4[t] = make_float4(my_disp, my_ent, my_rep, my_inter);
    __syncthreads();
    for (int off = 128; off >= 1; off >>= 1) {
        if (t < off) {
            const float4 a = red4[t], b = red4[t + off];
            red4[t] = make_float4(a.x + b.x, a.y + b.y, a.z + b.z, a.w + b.w);
        }
        __syncthreads();
    }
    if (t == 0) {
        atomicAdd(accs + 0, red4[0].x);
        atomicAdd(accs + 1, red4[0].y);
        atomicAdd(accs + 2, red4[0].z);
        atomicAdd(accs + 3, red4[0].w);
        __threadfence();
        const unsigned prev = __hip_atomic_fetch_add(
            reinterpret_cast<unsigned*>(accs + 4), 1u,
            __ATOMIC_ACQ_REL, __HIP_MEMORY_SCOPE_AGENT);
        if (prev == (unsigned)(F_DIM - 1)) {
            const float disp = __hip_atomic_load(accs + 0, __ATOMIC_RELAXED, __HIP_MEMORY_SCOPE_AGENT);
            const float ent  = __hip_atomic_load(accs + 1, __ATOMIC_RELAXED, __HIP_MEMORY_SCOPE_AGENT);
            const float rep  = __hip_atomic_load(accs + 2, __ATOMIC_RELAXED, __HIP_MEMORY_SCOPE_AGENT);
            const float inter = __hip_atomic_load(accs + 3, __ATOMIC_RELAXED, __HIP_MEMORY_SCOPE_AGENT)
                                * (1.0f / (float)F_DIM);
            out[0] = disp + 0.1f * ent + 0.5f * rep + 0.3f * inter;
            out[1] = disp;
            out[2] = ent;
            out[3] = rep;
            out[4] = inter;
        }
    }
}

extern "C" void kernel_launch(void* const* d_in, const int* in_sizes, int n_in,
                              void* d_out, int out_size, void* d_ws, size_t ws_size,
                              hipStream_t stream) {
    const float* M = (const float*)d_in[0];   // (16384, 64, 32) fp32
    const float* Y = (const float*)d_in[1];   // (16384, 128) fp32
    float* out = (float*)d_out;               // 5 floats
    char*  ws  = (char*)d_ws;

    const size_t ybfBytes = (size_t)9 * NB32 * 64 * 8 * sizeof(_Float16);  // 4,718,592
    const size_t wBytes   = (size_t)FK * CW * sizeof(float);               // 1,081,344

    _Float16* Ybf   = (_Float16*)ws;
    float*    W     = (float*)(ws + ybfBytes);
    float*    accs  = (float*)(ws + ybfBytes + wBytes);        // 4 sums + counter
    float*    wpart = (float*)(ws + ybfBytes + wBytes + 1024);

    // WS guard: halve nchunk until wpart fits. nchunk=32 -> ~40.4 MB total
    // (the round-0-proven footprint).
    const size_t used = ybfBytes + wBytes + 1024;
    int nchunk = 32;
    while (nchunk > 1 && used + (size_t)nchunk * wBytes > ws_size) nchunk >>= 1;
    const int cn = N_PTS / nchunk;   // 512 at nchunk=32; multiple of 64

    build_ybf_k<<<dim3(N_PTS / 64), dim3(256), 0, stream>>>(Y, Ybf, accs);
    gemm_k<<<dim3(16 * nchunk), dim3(256), 0, stream>>>(M, Ybf, wpart, cn, nchunk);
    reduce_w_k<<<dim3(FK * CW / 4 / 128), dim3(128), 0, stream>>>(wpart, W, nchunk);
    epilogue_k<<<dim3(F_DIM), dim3(256), 0, stream>>>(W, accs, out);
}